// Round 4
// baseline (52.398 us; speedup 1.0000x reference)
//
#include <hip/hip_runtime.h>

#define NPTS   2048
#define NROWS  (2 * NPTS)        // 4096
#define CCH    32
#define VOL_V  (64 * 128 * 128)  // 1048576
#define INV_T  (1.0f / 0.07f)
#define NCHUNK 8                 // j-chunks; 256 j-tiles / 8 = 32 tiles per chunk

typedef __attribute__((ext_vector_type(8))) short bf16x8;  // 8 bf16 = 4 VGPRs
typedef __attribute__((ext_vector_type(4))) float f32x4;

// ---------------------------------------------------------------------------
// K1: gather E_bf[r][c] = bf16(emb[c*V + ind(r)]); zero the arrival counter.
// ---------------------------------------------------------------------------
__global__ __launch_bounds__(256) void gather_k(
    const float* __restrict__ e0, const float* __restrict__ e1,
    const float* __restrict__ loc0, const float* __restrict__ loc1,
    unsigned short* __restrict__ Eb, int* __restrict__ cnt)
{
    int idx = blockIdx.x * 256 + threadIdx.x;   // 0 .. NROWS*CCH-1
    if (idx == 0) cnt[0] = 0;                   // reset last-block counter
    if (idx >= NROWS * CCH) return;
    int r = idx >> 5;
    int c = idx & 31;
    const float* loc = (r < NPTS) ? (loc0 + 3 * r) : (loc1 + 3 * (r - NPTS));
    const float* e   = (r < NPTS) ? e0 : e1;
    int ind = (int)loc[0] * 16384 + (int)loc[1] * 128 + (int)loc[2];
    float v = e[(size_t)c * VOL_V + ind];
    unsigned u = __builtin_bit_cast(unsigned, v);
    u += 0x7fff + ((u >> 16) & 1);              // RNE to bf16
    Eb[idx] = (unsigned short)(u >> 16);
}

// ---------------------------------------------------------------------------
// K2: MFMA row sums + fused finalize in the last-arriving block.
// Each wave owns 32 r-rows (2 A-frags) and one j-chunk (32 j-tiles of 16).
// Per tile: 1 coalesced 1KB B load + 2 mfma_16x16x32_bf16 + 8 exp.
// acc[q] of the 16x16 tile: (A-row = lgrp*4+q, B-row = lrow) — verified
// (absmax 0.0 in round 3; symmetric S makes transposition safe anyway).
// ---------------------------------------------------------------------------
__global__ __launch_bounds__(256) void rowsum_k(
    const unsigned short* __restrict__ Eb, float* __restrict__ partial,
    int* __restrict__ cnt, float* __restrict__ out)
{
    int lane    = threadIdx.x & 63;
    int wave_id = blockIdx.x * 4 + (threadIdx.x >> 6);
    int rstripe = wave_id & (NROWS / 32 - 1);   // 0..127
    int chunk   = wave_id >> 7;                 // 0..NCHUNK-1
    int r0      = rstripe * 32;

    int lrow = lane & 15;          // row/col within 16-tile
    int lgrp = lane >> 4;          // 0..3
    int koff = lgrp * 8;           // k-offset of this lane's 8 bf16

    bf16x8 a0 = *(const bf16x8*)(Eb + (size_t)(r0      + lrow) * CCH + koff);
    bf16x8 a1 = *(const bf16x8*)(Eb + (size_t)(r0 + 16 + lrow) * CCH + koff);

    float racc0[4] = {0.f, 0.f, 0.f, 0.f};
    float racc1[4] = {0.f, 0.f, 0.f, 0.f};
    int rg_base0 = r0      + lgrp * 4;          // global row of acc0[q] - q
    int rg_base1 = r0 + 16 + lgrp * 4;

    const f32x4 zero = {0.f, 0.f, 0.f, 0.f};

    #pragma unroll 4
    for (int t = 0; t < 256 / NCHUNK; ++t) {    // 32 tiles
        int j0 = (chunk * (256 / NCHUNK) + t) * 16;
        bf16x8 b = *(const bf16x8*)(Eb + (size_t)(j0 + lrow) * CCH + koff);
        f32x4 c0 = __builtin_amdgcn_mfma_f32_16x16x32_bf16(a0, b, zero, 0, 0, 0);
        f32x4 c1 = __builtin_amdgcn_mfma_f32_16x16x32_bf16(a1, b, zero, 0, 0, 0);
        int jg = j0 + lrow;
        #pragma unroll
        for (int q = 0; q < 4; ++q) {
            float ex0 = __expf(c0[q] * INV_T);
            float ex1 = __expf(c1[q] * INV_T);
            racc0[q] += (jg == rg_base0 + q) ? 0.0f : ex0;
            racc1[q] += (jg == rg_base1 + q) ? 0.0f : ex1;
        }
    }

    // reduce across the 16 lanes of each group (B-rows / cols of the tile)
    #pragma unroll
    for (int q = 0; q < 4; ++q) {
        #pragma unroll
        for (int m = 1; m < 16; m <<= 1) {
            racc0[q] += __shfl_xor(racc0[q], m);
            racc1[q] += __shfl_xor(racc1[q], m);
        }
    }
    if (lrow == 0) {
        #pragma unroll
        for (int q = 0; q < 4; ++q) {
            partial[(size_t)chunk * NROWS + rg_base0 + q] = racc0[q];
            partial[(size_t)chunk * NROWS + rg_base1 + q] = racc1[q];
        }
    }

    // ---- last-block finalize -------------------------------------------
    __threadfence();                 // release our partial stores (device scope)
    __syncthreads();
    __shared__ int is_last;
    if (threadIdx.x == 0)
        is_last = (atomicAdd(cnt, 1) == (int)gridDim.x - 1);
    __syncthreads();
    if (!is_last) return;
    __threadfence();                 // acquire: see all blocks' partials

    float lsum = 0.0f;
    #pragma unroll 2
    for (int rr = 0; rr < NROWS / 256; ++rr) {   // 16 rows per thread
        int r = rr * 256 + threadIdx.x;
        float rs = 0.0f;
        #pragma unroll
        for (int ch = 0; ch < NCHUNK; ++ch)
            rs += partial[(size_t)ch * NROWS + r];

        int p = r ^ NPTS;                        // pair row
        const bf16x8* er = (const bf16x8*)(Eb + (size_t)r * CCH);
        const bf16x8* ep = (const bf16x8*)(Eb + (size_t)p * CCH);
        float s = 0.0f;
        #pragma unroll
        for (int i = 0; i < 4; ++i) {
            bf16x8 va = er[i], vb = ep[i];
            #pragma unroll
            for (int k = 0; k < 8; ++k) {
                float fa = __builtin_bit_cast(float, (unsigned)(unsigned short)va[k] << 16);
                float fb = __builtin_bit_cast(float, (unsigned)(unsigned short)vb[k] << 16);
                s = fmaf(fa, fb, s);
            }
        }
        lsum += s * INV_T - __logf(rs);
    }

    __shared__ float red[256];
    red[threadIdx.x] = lsum;
    __syncthreads();
    #pragma unroll
    for (int off = 128; off > 0; off >>= 1) {
        if (threadIdx.x < off) red[threadIdx.x] += red[threadIdx.x + off];
        __syncthreads();
    }
    if (threadIdx.x == 0)
        out[0] = -red[0] / (2.0f * NPTS);
}

// ---------------------------------------------------------------------------
extern "C" void kernel_launch(void* const* d_in, const int* in_sizes, int n_in,
                              void* d_out, int out_size, void* d_ws, size_t ws_size,
                              hipStream_t stream)
{
    const float* e0 = (const float*)d_in[0];
    const float* e1 = (const float*)d_in[1];
    const float* l0 = (const float*)d_in[2];
    const float* l1 = (const float*)d_in[3];
    float* out = (float*)d_out;

    unsigned short* Eb = (unsigned short*)d_ws;                        // 256 KB
    float* partial = (float*)((char*)d_ws + (size_t)NROWS * CCH * 2);  // 128 KB
    int* cnt = (int*)((char*)d_ws + (size_t)NROWS * CCH * 2
                                  + (size_t)NCHUNK * NROWS * 4);       // 4 B

    gather_k<<<(NROWS * CCH + 255) / 256, 256, 0, stream>>>(e0, e1, l0, l1, Eb, cnt);

    // (NROWS/32) stripes * NCHUNK chunks waves, 4 waves per block = 256 blocks
    int nblocks = (NROWS / 32) * NCHUNK / 4;
    rowsum_k<<<nblocks, 256, 0, stream>>>(Eb, partial, cnt, out);
}

// Round 5
// 34.925 us; speedup vs baseline: 1.5003x; 1.5003x over previous
//
#include <hip/hip_runtime.h>

#define NPTS   2048
#define NROWS  (2 * NPTS)        // 4096
#define CCH    32
#define VOL_V  (64 * 128 * 128)  // 1048576
#define INV_T  (1.0f / 0.07f)

typedef __attribute__((ext_vector_type(8))) short bf16x8;  // 8 bf16 = 4 VGPRs
typedef __attribute__((ext_vector_type(4))) float f32x4;

// ---------------------------------------------------------------------------
// K1: gather E_bf[r][c] = bf16(emb[c*V + ind(r)]); zero d_out (stream-ordered
// before K2's atomics; re-zeroed every launch => graph replays deterministic).
// ---------------------------------------------------------------------------
__global__ __launch_bounds__(256) void gather_k(
    const float* __restrict__ e0, const float* __restrict__ e1,
    const float* __restrict__ loc0, const float* __restrict__ loc1,
    unsigned short* __restrict__ Eb, float* __restrict__ out)
{
    int idx = blockIdx.x * 256 + threadIdx.x;   // 0 .. NROWS*CCH-1
    if (idx == 0) out[0] = 0.0f;
    if (idx >= NROWS * CCH) return;
    int r = idx >> 5;
    int c = idx & 31;
    const float* loc = (r < NPTS) ? (loc0 + 3 * r) : (loc1 + 3 * (r - NPTS));
    const float* e   = (r < NPTS) ? e0 : e1;
    int ind = (int)loc[0] * 16384 + (int)loc[1] * 128 + (int)loc[2];
    float v = e[(size_t)c * VOL_V + ind];
    unsigned u = __builtin_bit_cast(unsigned, v);
    u += 0x7fff + ((u >> 16) & 1);              // RNE to bf16
    Eb[idx] = (unsigned short)(u >> 16);
}

// ---------------------------------------------------------------------------
// K2: fused rowsum + finalize, block-local only (no device fences).
// Each block owns one 16-row stripe; its 4 waves split the 256 j-tiles
// (64 each). Per tile: 1 coalesced 1KB B load + 1 mfma_16x16x32_bf16 +
// 4 exp + diag-skip + pair-capture. Waves combine via 512B LDS +
// __syncthreads; one atomicAdd per block.
// acc[q] layout (verified round 3, absmax 0.0): S[A-row = lgrp*4+q][B-row = lrow].
// ---------------------------------------------------------------------------
__global__ __launch_bounds__(256) void rowsum_k(
    const unsigned short* __restrict__ Eb, float* __restrict__ out)
{
    int lane = threadIdx.x & 63;
    int w    = threadIdx.x >> 6;        // 0..3: j-chunk of this wave
    int r0   = blockIdx.x * 16;         // this block's row stripe
    int lrow = lane & 15;
    int lgrp = lane >> 4;               // 0..3
    int koff = lgrp * 8;                // k-offset of this lane's 8 bf16

    bf16x8 a = *(const bf16x8*)(Eb + (size_t)(r0 + lrow) * CCH + koff);

    float racc[4]  = {0.f, 0.f, 0.f, 0.f};
    float pairv[4] = {0.f, 0.f, 0.f, 0.f};
    int rg = r0 + lgrp * 4;             // global row of acc[q] - q

    const f32x4 zero = {0.f, 0.f, 0.f, 0.f};

    #pragma unroll 8
    for (int t = 0; t < 64; ++t) {
        int j0 = (w * 64 + t) * 16;
        bf16x8 b = *(const bf16x8*)(Eb + (size_t)(j0 + lrow) * CCH + koff);
        f32x4 c = __builtin_amdgcn_mfma_f32_16x16x32_bf16(a, b, zero, 0, 0, 0);
        int jg = j0 + lrow;             // global column of c[*] for this lane
        #pragma unroll
        for (int q = 0; q < 4; ++q) {
            float ex = __expf(c[q] * INV_T);
            racc[q] += (jg == rg + q) ? 0.0f : ex;                   // skip diag
            pairv[q] = (jg == ((rg + q) ^ NPTS)) ? c[q] : pairv[q];  // capture s_pair
        }
    }

    // reduce across the 16 B-row lanes (columns of the tile)
    #pragma unroll
    for (int q = 0; q < 4; ++q) {
        #pragma unroll
        for (int m = 1; m < 16; m <<= 1) {
            racc[q]  += __shfl_xor(racc[q], m);
            pairv[q] += __shfl_xor(pairv[q], m);   // exactly one nonzero lane
        }
    }

    __shared__ float lds_rs[4][16];
    __shared__ float lds_ps[4][16];
    if (lrow == 0) {
        #pragma unroll
        for (int q = 0; q < 4; ++q) {
            lds_rs[w][lgrp * 4 + q] = racc[q];
            lds_ps[w][lgrp * 4 + q] = pairv[q];
        }
    }
    __syncthreads();

    if (threadIdx.x < 16) {
        int row = threadIdx.x;
        float rs = lds_rs[0][row] + lds_rs[1][row] + lds_rs[2][row] + lds_rs[3][row];
        float ps = lds_ps[0][row] + lds_ps[1][row] + lds_ps[2][row] + lds_ps[3][row];
        float contrib = ps * INV_T - __logf(rs);
        #pragma unroll
        for (int m = 1; m < 16; m <<= 1)
            contrib += __shfl_xor(contrib, m);
        if (row == 0)
            atomicAdd(out, -contrib / (2.0f * NPTS));
    }
}

// ---------------------------------------------------------------------------
extern "C" void kernel_launch(void* const* d_in, const int* in_sizes, int n_in,
                              void* d_out, int out_size, void* d_ws, size_t ws_size,
                              hipStream_t stream)
{
    const float* e0 = (const float*)d_in[0];
    const float* e1 = (const float*)d_in[1];
    const float* l0 = (const float*)d_in[2];
    const float* l1 = (const float*)d_in[3];
    float* out = (float*)d_out;

    unsigned short* Eb = (unsigned short*)d_ws;   // 256 KB

    gather_k<<<(NROWS * CCH) / 256, 256, 0, stream>>>(e0, e1, l0, l1, Eb, out);

    rowsum_k<<<NROWS / 16, 256, 0, stream>>>(Eb, out);  // 256 blocks x 4 waves
}

// Round 7
// 23.100 us; speedup vs baseline: 2.2683x; 1.5119x over previous
//
#include <hip/hip_runtime.h>

#define NPTS   2048
#define NROWS  (2 * NPTS)        // 4096
#define CCH    32
#define VOL_V  (64 * 128 * 128)  // 1048576
#define INV_T  (1.0f / 0.07f)
#define SCALE  (INV_T * 1.4426950408889634f)   // 1/(T*ln2): exp(s/T)=exp2(s*SCALE)

typedef __attribute__((ext_vector_type(8))) short bf16x8;  // 8 bf16 = 4 VGPRs
typedef __attribute__((ext_vector_type(4))) float f32x4;

// ---------------------------------------------------------------------------
// K1: gather E_bf[r][c] = bf16(emb[c*V + ind(r)]); zero d_out (stream-ordered
// before K2's atomics; re-zeroed every launch => graph replays deterministic).
// ---------------------------------------------------------------------------
__global__ __launch_bounds__(256) void gather_k(
    const float* __restrict__ e0, const float* __restrict__ e1,
    const float* __restrict__ loc0, const float* __restrict__ loc1,
    unsigned short* __restrict__ Eb, float* __restrict__ out)
{
    int idx = blockIdx.x * 256 + threadIdx.x;   // 0 .. NROWS*CCH-1
    if (idx == 0) out[0] = 0.0f;
    if (idx >= NROWS * CCH) return;
    int r = idx >> 5;
    int c = idx & 31;
    const float* loc = (r < NPTS) ? (loc0 + 3 * r) : (loc1 + 3 * (r - NPTS));
    const float* e   = (r < NPTS) ? e0 : e1;
    int ind = (int)loc[0] * 16384 + (int)loc[1] * 128 + (int)loc[2];
    float v = e[(size_t)c * VOL_V + ind];
    unsigned u = __builtin_bit_cast(unsigned, v);
    u += 0x7fff + ((u >> 16) & 1);              // RNE to bf16
    Eb[idx] = (unsigned short)(u >> 16);
}

// ---------------------------------------------------------------------------
// K2: fused rowsum + finalize, block-local only (no device fences).
// Each block owns one 16-row stripe; its 16 waves (1024 thr) split the 256
// j-tiles (16 each) => 4096 waves = 4/SIMD chip-wide, short dependent chains.
// Per tile: 1 coalesced 1KB B load + 1 mfma_16x16x32_bf16 + 4 exp2 +
// diag-skip + pair-capture. Waves combine via 2KB LDS + one __syncthreads;
// one atomicAdd per block (256 total — validated absmax 0.0 in round 5).
// acc[q] layout (verified round 3): S[A-row = lgrp*4+q][B-row = lrow].
// ---------------------------------------------------------------------------
__global__ __launch_bounds__(1024) void rowsum_k(
    const unsigned short* __restrict__ Eb, float* __restrict__ out)
{
    int lane = threadIdx.x & 63;
    int w    = threadIdx.x >> 6;        // 0..15: j-chunk of this wave
    int r0   = blockIdx.x * 16;         // this block's row stripe
    int lrow = lane & 15;
    int lgrp = lane >> 4;               // 0..3
    int koff = lgrp * 8;                // k-offset of this lane's 8 bf16

    bf16x8 a = *(const bf16x8*)(Eb + (size_t)(r0 + lrow) * CCH + koff);

    float racc[4]  = {0.f, 0.f, 0.f, 0.f};
    float pairv[4] = {0.f, 0.f, 0.f, 0.f};
    int rg = r0 + lgrp * 4;             // global row of acc[q] - q

    const f32x4 zero = {0.f, 0.f, 0.f, 0.f};

    #pragma unroll
    for (int t = 0; t < 16; ++t) {
        int j0 = (w * 16 + t) * 16;
        bf16x8 b = *(const bf16x8*)(Eb + (size_t)(j0 + lrow) * CCH + koff);
        f32x4 c = __builtin_amdgcn_mfma_f32_16x16x32_bf16(a, b, zero, 0, 0, 0);
        int jg = j0 + lrow;             // global column of c[*] for this lane
        #pragma unroll
        for (int q = 0; q < 4; ++q) {
            float ex = exp2f(c[q] * SCALE);
            racc[q] += (jg == rg + q) ? 0.0f : ex;                   // skip diag
            pairv[q] = (jg == ((rg + q) ^ NPTS)) ? c[q] : pairv[q];  // capture s_pair
        }
    }

    // reduce across the 16 B-row lanes (columns of the tile)
    #pragma unroll
    for (int q = 0; q < 4; ++q) {
        #pragma unroll
        for (int m = 1; m < 16; m <<= 1) {
            racc[q]  += __shfl_xor(racc[q], m);
            pairv[q] += __shfl_xor(pairv[q], m);   // exactly one nonzero lane
        }
    }

    __shared__ float lds_rs[16][16];
    __shared__ float lds_ps[16][16];
    if (lrow == 0) {
        #pragma unroll
        for (int q = 0; q < 4; ++q) {
            lds_rs[w][lgrp * 4 + q] = racc[q];
            lds_ps[w][lgrp * 4 + q] = pairv[q];
        }
    }
    __syncthreads();

    if (threadIdx.x < 16) {
        int row = threadIdx.x;
        float rs = 0.f, ps = 0.f;
        #pragma unroll
        for (int ww = 0; ww < 16; ++ww) {
            rs += lds_rs[ww][row];
            ps += lds_ps[ww][row];
        }
        float contrib = ps * INV_T - __logf(rs);
        #pragma unroll
        for (int m = 1; m < 16; m <<= 1)
            contrib += __shfl_xor(contrib, m);
        if (row == 0)
            atomicAdd(out, -contrib / (2.0f * NPTS));
    }
}

// ---------------------------------------------------------------------------
extern "C" void kernel_launch(void* const* d_in, const int* in_sizes, int n_in,
                              void* d_out, int out_size, void* d_ws, size_t ws_size,
                              hipStream_t stream)
{
    const float* e0 = (const float*)d_in[0];
    const float* e1 = (const float*)d_in[1];
    const float* l0 = (const float*)d_in[2];
    const float* l1 = (const float*)d_in[3];
    float* out = (float*)d_out;

    unsigned short* Eb = (unsigned short*)d_ws;   // 256 KB

    gather_k<<<(NROWS * CCH) / 256, 256, 0, stream>>>(e0, e1, l0, l1, Eb, out);

    rowsum_k<<<NROWS / 16, 1024, 0, stream>>>(Eb, out);  // 256 blocks x 16 waves
}

// Round 8
// 21.851 us; speedup vs baseline: 2.3979x; 1.0572x over previous
//
#include <hip/hip_runtime.h>

#define NPTS   2048
#define NROWS  (2 * NPTS)        // 4096
#define CCH    32
#define VOL_V  (64 * 128 * 128)  // 1048576
#define INV_T  (1.0f / 0.07f)
#define SCALE  (INV_T * 1.4426950408889634f)   // 1/(T*ln2): exp(s/T)=exp2(s*SCALE)

typedef __attribute__((ext_vector_type(8))) short bf16x8;  // 8 bf16 = 4 VGPRs
typedef __attribute__((ext_vector_type(4))) float f32x4;

// ---------------------------------------------------------------------------
// K1: gather E_bf[r][c] = bf16(emb[c*V + ind(r)]); zero d_out (stream-ordered
// before K2's atomics; re-zeroed every launch => graph replays deterministic).
// Volume reads are single-use -> nontemporal to keep L2 for Eb.
// ---------------------------------------------------------------------------
__global__ __launch_bounds__(256) void gather_k(
    const float* __restrict__ e0, const float* __restrict__ e1,
    const float* __restrict__ loc0, const float* __restrict__ loc1,
    unsigned short* __restrict__ Eb, float* __restrict__ out)
{
    int idx = blockIdx.x * 256 + threadIdx.x;   // 0 .. NROWS*CCH-1
    if (idx == 0) out[0] = 0.0f;
    if (idx >= NROWS * CCH) return;
    int r = idx >> 5;
    int c = idx & 31;
    const float* loc = (r < NPTS) ? (loc0 + 3 * r) : (loc1 + 3 * (r - NPTS));
    const float* e   = (r < NPTS) ? e0 : e1;
    int ind = (int)loc[0] * 16384 + (int)loc[1] * 128 + (int)loc[2];
    float v = __builtin_nontemporal_load(e + (size_t)c * VOL_V + ind);
    unsigned u = __builtin_bit_cast(unsigned, v);
    u += 0x7fff + ((u >> 16) & 1);              // RNE to bf16
    Eb[idx] = (unsigned short)(u >> 16);
}

// ---------------------------------------------------------------------------
// K2: fused rowsum + finalize, block-local only (no device fences).
// Each block owns one 16-row stripe; its 16 waves (1024 thr) split the 256
// j-tiles (16 each) => 4096 waves = 4/SIMD chip-wide.
// Wave-uniform tile specialization: for block bid, the diagonal can only be
// in global tile bid and the pair column only in tile bid^128 — all other
// tiles take a compare-free fast path (saves ~16 VALU ops/tile-lane).
// acc[q] layout (verified rounds 3/5/7, absmax 0.0): S[A-row=lgrp*4+q][B-row=lrow].
// ---------------------------------------------------------------------------
__global__ __launch_bounds__(1024) void rowsum_k(
    const unsigned short* __restrict__ Eb, float* __restrict__ out)
{
    int lane = threadIdx.x & 63;
    int w    = threadIdx.x >> 6;        // 0..15: j-chunk of this wave
    int bid  = blockIdx.x;
    int r0   = bid * 16;                // this block's row stripe
    int lrow = lane & 15;
    int lgrp = lane >> 4;               // 0..3
    int koff = lgrp * 8;                // k-offset of this lane's 8 bf16

    bf16x8 a = *(const bf16x8*)(Eb + (size_t)(r0 + lrow) * CCH + koff);

    float racc[4]  = {0.f, 0.f, 0.f, 0.f};
    float pairv[4] = {0.f, 0.f, 0.f, 0.f};
    int rg = r0 + lgrp * 4;             // global row of acc[q] - q

    const f32x4 zero = {0.f, 0.f, 0.f, 0.f};
    int diag_t = bid;                   // tile holding S[r][r]
    int pair_t = bid ^ (NPTS / 16);     // tile holding S[r][r^NPTS]

    #pragma unroll 4
    for (int t = 0; t < 16; ++t) {
        int tg = w * 16 + t;            // global tile index (wave-uniform)
        int j0 = tg * 16;
        bf16x8 b = *(const bf16x8*)(Eb + (size_t)(j0 + lrow) * CCH + koff);
        f32x4 c = __builtin_amdgcn_mfma_f32_16x16x32_bf16(a, b, zero, 0, 0, 0);
        if (tg == diag_t || tg == pair_t) {          // wave-uniform branch
            int jg = j0 + lrow;
            #pragma unroll
            for (int q = 0; q < 4; ++q) {
                float ex = exp2f(c[q] * SCALE);
                racc[q] += (jg == rg + q) ? 0.0f : ex;                   // skip diag
                pairv[q] = (jg == ((rg + q) ^ NPTS)) ? c[q] : pairv[q];  // s_pair
            }
        } else {                                      // fast path: 254/256 tiles
            #pragma unroll
            for (int q = 0; q < 4; ++q)
                racc[q] += exp2f(c[q] * SCALE);
        }
    }

    // reduce across the 16 B-row lanes (columns of the tile)
    #pragma unroll
    for (int q = 0; q < 4; ++q) {
        #pragma unroll
        for (int m = 1; m < 16; m <<= 1) {
            racc[q]  += __shfl_xor(racc[q], m);
            pairv[q] += __shfl_xor(pairv[q], m);   // exactly one nonzero lane
        }
    }

    __shared__ float lds_rs[16][16];
    __shared__ float lds_ps[16][16];
    if (lrow == 0) {
        #pragma unroll
        for (int q = 0; q < 4; ++q) {
            lds_rs[w][lgrp * 4 + q] = racc[q];
            lds_ps[w][lgrp * 4 + q] = pairv[q];
        }
    }
    __syncthreads();

    if (threadIdx.x < 16) {
        int row = threadIdx.x;
        float rs = 0.f, ps = 0.f;
        #pragma unroll
        for (int ww = 0; ww < 16; ++ww) {
            rs += lds_rs[ww][row];
            ps += lds_ps[ww][row];
        }
        float contrib = ps * INV_T - __logf(rs);
        #pragma unroll
        for (int m = 1; m < 16; m <<= 1)
            contrib += __shfl_xor(contrib, m);
        if (row == 0)
            atomicAdd(out, -contrib / (2.0f * NPTS));
    }
}

// ---------------------------------------------------------------------------
extern "C" void kernel_launch(void* const* d_in, const int* in_sizes, int n_in,
                              void* d_out, int out_size, void* d_ws, size_t ws_size,
                              hipStream_t stream)
{
    const float* e0 = (const float*)d_in[0];
    const float* e1 = (const float*)d_in[1];
    const float* l0 = (const float*)d_in[2];
    const float* l1 = (const float*)d_in[3];
    float* out = (float*)d_out;

    unsigned short* Eb = (unsigned short*)d_ws;   // 256 KB

    gather_k<<<(NROWS * CCH) / 256, 256, 0, stream>>>(e0, e1, l0, l1, Eb, out);

    rowsum_k<<<NROWS / 16, 1024, 0, stream>>>(Eb, out);  // 256 blocks x 16 waves
}